// Round 9
// baseline (230.351 us; speedup 1.0000x reference)
//
#include <hip/hip_runtime.h>
#include <hip/hip_fp16.h>
#include <math.h>

// Fixed-capacity bucketed CSR build (per-tile LDS counting sort -> coalesced
// bucket writes), then node-parallel coalesced gather aggregation with fp16
// gather tables (hw1h 3.2 MB, hw2h 1.6 MB -> L2-resident).
// gemm1 (x@W1, dinv-prescaled) via MFMA f32_16x16x32_f16.
// R1: wave-shuffle scans. R3: quad-split agg. R5: masked tails + idx prefetch
//     (BEST: 206.9 us — agg kernels here are exact R5).
// R6 (REVERTED): LDS-atomic agg. R7/R8 (REVERTED): padded-int4 / hybrid lane
//     map both neutral — agg is at its request/latency floor.
// R9: CSR-build LOAD BALANCE. binscatter: TILE 8192->4096, 512 thr, 30 KB LDS
//     -> 4 blocks/CU, 782 blocks ~= 1 round (was 391 blk @ 2/CU = 2 rounds,
//     76% util). sortbucket: BSHIFT 8->7 (BUCK=128, NBUK=782, CAP=6144, same
//     total footprint), 512 thr -> 1 round. Pair-scan covers 1024 buckets
//     with 512 threads, no guard divergence.
#define BSHIFT 7
#define BUCK   128
#define TILE   4096     // edges per scatter workgroup (512 threads, 8 edges/thread)
#define CAP    6144     // bucket capacity; mean 4092, sigma 64 -> 32 sigma headroom

typedef _Float16 f16x2 __attribute__((ext_vector_type(2)));
typedef _Float16 f16x4 __attribute__((ext_vector_type(4)));
typedef _Float16 f16x8 __attribute__((ext_vector_type(8)));
typedef float    f32x4 __attribute__((ext_vector_type(4)));

// ---------------- CSR build ----------------

__global__ __launch_bounds__(256) void k_curinit(int* __restrict__ bcursor, int nbuk) {
    int b = blockIdx.x * 256 + threadIdx.x;
    if (b < nbuk) bcursor[b] = b * CAP;
}

// tile scatter with full per-tile LDS counting sort by bucket, so the global
// binned[] writes are lane-consecutive (coalesced bursts per bucket run).
// packed edge = (dst&127)<<17 | src   (src < 2^17)
__global__ __launch_bounds__(512) void k_binscatter(const int* __restrict__ src,
                                                    const int* __restrict__ dst,
                                                    int* __restrict__ bcursor,
                                                    int* __restrict__ binned, int E, int nbuk) {
    __shared__ int            payload[TILE];   // 16 KB
    __shared__ unsigned short bid16[TILE];     // 8 KB
    __shared__ int cnt[1024];                  // hist -> local cursor (4 KB)
    __shared__ int lstart[1024];               // exclusive scan (local base)
    __shared__ int gbase[1024];                // reserved global base
    __shared__ int wsum[8];
    int t = threadIdx.x;
    int tile0 = blockIdx.x * TILE;
    int tileE = min(TILE, E - tile0);
    cnt[t] = 0; cnt[t + 512] = 0;
    __syncthreads();
    // load 8 edges/thread (vectorized when full)
    int d[8], s[8];
    int base = t * 8;
    if (base + 8 <= tileE) {
        const int4* d4 = (const int4*)(dst + tile0 + base);
        const int4* s4 = (const int4*)(src + tile0 + base);
        int4 da = d4[0], db = d4[1];
        int4 sa = s4[0], sb = s4[1];
        d[0] = da.x; d[1] = da.y; d[2] = da.z; d[3] = da.w;
        d[4] = db.x; d[5] = db.y; d[6] = db.z; d[7] = db.w;
        s[0] = sa.x; s[1] = sa.y; s[2] = sa.z; s[3] = sa.w;
        s[4] = sb.x; s[5] = sb.y; s[6] = sb.z; s[7] = sb.w;
    } else {
#pragma unroll
        for (int q = 0; q < 8; ++q) {
            int idx = base + q;
            if (idx < tileE) { d[q] = dst[tile0 + idx]; s[q] = src[tile0 + idx]; }
            else d[q] = -1;
        }
    }
#pragma unroll
    for (int q = 0; q < 8; ++q)
        if (d[q] >= 0) atomicAdd(&cnt[d[q] >> BSHIFT], 1);
    __syncthreads();
    // pair-scan: 512 threads scan 1024 buckets (2 consecutive per thread).
    // wave-shuffle inclusive scan of pair sums, then thread 0 combines waves.
    int c0 = cnt[2 * t], c1 = cnt[2 * t + 1];
    int p = c0 + c1;
    int v = p;
#pragma unroll
    for (int off = 1; off < 64; off <<= 1) {
        int u = __shfl_up(v, off, 64);
        if ((t & 63) >= off) v += u;
    }
    if ((t & 63) == 63) wsum[t >> 6] = v;
    int ex = v - p;                             // exclusive pair base (in-wave)
    __syncthreads();
    if (t == 0) {
        int run = 0;
#pragma unroll
        for (int w = 0; w < 8; ++w) { int u = wsum[w]; wsum[w] = run; run += u; }
    }
    __syncthreads();
    ex += wsum[t >> 6];
    lstart[2 * t]     = ex;
    lstart[2 * t + 1] = ex + c0;
    gbase[2 * t]     = c0 ? atomicAdd(&bcursor[2 * t], c0) : 0;
    gbase[2 * t + 1] = c1 ? atomicAdd(&bcursor[2 * t + 1], c1) : 0;
    __syncthreads();                            // lstart published before reuse
    cnt[2 * t]     = ex;                        // local cursors
    cnt[2 * t + 1] = ex + c0;
    __syncthreads();
    // LDS scatter: sort tile's edges by bucket
#pragma unroll
    for (int q = 0; q < 8; ++q) {
        if (d[q] >= 0) {
            int b = d[q] >> BSHIFT;
            int lp = atomicAdd(&cnt[b], 1);
            payload[lp] = ((d[q] & (BUCK - 1)) << 17) | s[q];
            bid16[lp] = (unsigned short)b;
        }
    }
    __syncthreads();
    // coalesced copy-out: consecutive k -> consecutive global addresses
    for (int k = t; k < tileE; k += 512) {
        int b = bid16[k];
        int ga = gbase[b] + (k - lstart[b]);
        if (ga < (b + 1) * CAP)                 // overflow guard (32 sigma)
            binned[ga] = payload[k];
    }
}

// per-bucket counting sort -> csr_src (dst-sorted, sparse layout),
// rowstart/rowend, dinv. One bucket (128 nodes) per 512-thread block.
__global__ __launch_bounds__(512) void k_sortbucket(const int* __restrict__ bcursor,
                                                    const int* __restrict__ binned,
                                                    int* __restrict__ csr_src,
                                                    int* __restrict__ rowstart,
                                                    int* __restrict__ rowend,
                                                    float* __restrict__ dinv, int N) {
    __shared__ int cnt[BUCK];
    __shared__ int cur[BUCK];
    __shared__ int wsum[2];
    int b = blockIdx.x, t = threadIdx.x;
    if (t < BUCK) cnt[t] = 0;
    __syncthreads();
    int beg = b * CAP;
    int end = min(bcursor[b], beg + CAP);
    int v[12];                                  // 12 * 512 = 6144 = CAP
#pragma unroll
    for (int q = 0; q < 12; ++q) {
        int e = beg + q * 512 + t;
        v[q] = (e < end) ? binned[e] : -1;
    }
#pragma unroll
    for (int q = 0; q < 12; ++q)
        if (v[q] >= 0) atomicAdd(&cnt[v[q] >> 17], 1);
    __syncthreads();
    // wave-shuffle exclusive scan over cnt[128] (2 waves + combine)
    int c = 0, ex = 0;
    if (t < BUCK) {
        c = cnt[t];
        int s = c;
#pragma unroll
        for (int off = 1; off < 64; off <<= 1) {
            int u = __shfl_up(s, off, 64);
            if ((t & 63) >= off) s += u;
        }
        if ((t & 63) == 63) wsum[t >> 6] = s;
        ex = s - c;
    }
    __syncthreads();
    if (t == 0) { int u = wsum[0]; wsum[0] = 0; wsum[1] = u; }
    __syncthreads();
    if (t < BUCK) {
        ex += wsum[t >> 6];
        cur[t] = ex;
        int node = b * BUCK + t;
        if (node < N) {
            rowstart[node] = beg + ex;
            rowend[node]   = beg + ex + c;
            dinv[node] = rsqrtf((float)(c + 1));   // +1 self loop
        }
    }
    __syncthreads();
#pragma unroll
    for (int q = 0; q < 12; ++q) {
        if (v[q] >= 0) {
            int pos = atomicAdd(&cur[v[q] >> 17], 1);
            csr_src[beg + pos] = v[q] & 0x1FFFF;
        }
    }
}

// ---------------- layer compute ----------------

// hw1h[i,:] = fp16( dinv[i] * (x[i,:] @ W1) ) via MFMA 16x16x32 f16.
__global__ __launch_bounds__(256) void k_gemm1(const float* __restrict__ x,
                                               const float* __restrict__ W1,
                                               const float* __restrict__ dinv,
                                               __half* __restrict__ hw1h, int N) {
    __shared__ _Float16 sX[64 * 136];   // x tile fp16, row pad 136
    __shared__ _Float16 sW[16 * 136];   // W1^T fp16
    __shared__ float    sDi[64];
    __shared__ _Float16 sOut[64 * 16];
    int t = threadIdx.x;
    int row0 = blockIdx.x * 64;
    for (int e = t; e < 2048; e += 256) {
        int n = e & 15, k = e >> 4;
        sW[n * 136 + k] = (_Float16)W1[k * 16 + n];
    }
    const float4* x4 = (const float4*)x;
#pragma unroll
    for (int q = 0; q < 8; ++q) {
        int e = q * 256 + t;
        int r = e >> 5, c4 = e & 31;
        int gr = row0 + r;
        float4 v = (gr < N) ? x4[(size_t)gr * 32 + c4] : make_float4(0.f, 0.f, 0.f, 0.f);
        f16x4 hv = {(_Float16)v.x, (_Float16)v.y, (_Float16)v.z, (_Float16)v.w};
        *(f16x4*)&sX[r * 136 + c4 * 4] = hv;   // one ds_write_b64 (8B-aligned)
    }
    if (t < 64) sDi[t] = (row0 + t < N) ? dinv[row0 + t] : 0.f;
    __syncthreads();
    int w = t >> 6, l = t & 63;
    int m = l & 15, quad = l >> 4;
    f32x4 acc = {0.f, 0.f, 0.f, 0.f};
#pragma unroll
    for (int kc = 0; kc < 4; ++kc) {
        f16x8 a = *(const f16x8*)&sX[(w * 16 + m) * 136 + kc * 32 + quad * 8];
        f16x8 b = *(const f16x8*)&sW[m * 136 + kc * 32 + quad * 8];
        acc = __builtin_amdgcn_mfma_f32_16x16x32_f16(a, b, acc, 0, 0, 0);
    }
#pragma unroll
    for (int r = 0; r < 4; ++r) {
        int nl = w * 16 + quad * 4 + r;
        sOut[nl * 16 + m] = (_Float16)(acc[r] * sDi[nl]);
    }
    __syncthreads();
    int nn = t >> 2, ch = t & 3;
    int gn = row0 + nn;
    if (gn < N)
        *(float2*)&hw1h[(size_t)gn * 16 + ch * 4] = *(float2*)&sOut[nn * 16 + ch * 4];
}

// layer-1 (exact R5): 4 lanes/node, quad-split edge list, 2-deep index
// prefetch, masked full-width final chunk, shfl_xor butterfly merge, fused
// register GEMM2 (lane j -> out dims 2j,2j+1) -> hw2h (fp16, dinv-prescaled).
__global__ __launch_bounds__(256) void k_agg1c(const int* __restrict__ rowstart,
                                               const int* __restrict__ rowend,
                                               const int* __restrict__ csr_src,
                                               const f16x8* __restrict__ hw1v,
                                               const float* __restrict__ W2,
                                               const float* __restrict__ b1,
                                               __half* __restrict__ hw2h, int N) {
    __shared__ float sW[128], sb[16];
    int t = threadIdx.x;
    if (t < 128) sW[t] = W2[t];
    if (t < 16)  sb[t] = b1[t];
    __syncthreads();
    int q = t >> 2, j = t & 3;
    int i = blockIdx.x * 64 + q;
    if (i >= N) return;
    int beg = rowstart[i], end = rowend[i];
    int deg = end - beg;
    float di = rsqrtf((float)(deg + 1));
    float a[16];
#pragma unroll
    for (int d = 0; d < 16; ++d) a[d] = 0.f;
    int nfull = deg >> 4;
    int base0 = beg + 4 * j;
    int s4[4];
    if (nfull > 0) {
#pragma unroll
        for (int m = 0; m < 4; ++m) s4[m] = csr_src[base0 + m];
    }
    for (int ch = 0; ch < nfull; ++ch) {
        f16x8 lo[4], hi[4];
#pragma unroll
        for (int m = 0; m < 4; ++m) {
            lo[m] = hw1v[2 * (size_t)s4[m]];
            hi[m] = hw1v[2 * (size_t)s4[m] + 1];
        }
        int sn[4];
        if (ch + 1 < nfull) {      // prefetch next chunk's indices under gathers
#pragma unroll
            for (int m = 0; m < 4; ++m) sn[m] = csr_src[base0 + (ch + 1) * 16 + m];
        }
#pragma unroll
        for (int m = 0; m < 4; ++m) {
#pragma unroll
            for (int d = 0; d < 8; ++d) {
                a[d]     += (float)lo[m][d];
                a[8 + d] += (float)hi[m][d];
            }
        }
        if (ch + 1 < nfull) {
#pragma unroll
            for (int m = 0; m < 4; ++m) s4[m] = sn[m];
        }
    }
    if (deg & 15) {                // masked full-width final chunk
        int cb = beg + nfull * 16 + 4 * j;
        int   sr[4];
        float wr[4];
#pragma unroll
        for (int m = 0; m < 4; ++m) {
            int c = cb + m;
            bool ok = c < end;
            sr[m] = ok ? csr_src[c] : i;   // dummy = self row (hot line), weight 0
            wr[m] = ok ? 1.f : 0.f;
        }
        f16x8 lo[4], hi[4];
#pragma unroll
        for (int m = 0; m < 4; ++m) {
            lo[m] = hw1v[2 * (size_t)sr[m]];
            hi[m] = hw1v[2 * (size_t)sr[m] + 1];
        }
#pragma unroll
        for (int m = 0; m < 4; ++m) {
#pragma unroll
            for (int d = 0; d < 8; ++d) {
                a[d]     += wr[m] * (float)lo[m][d];
                a[8 + d] += wr[m] * (float)hi[m][d];
            }
        }
    }
    if (j == 0) {   // self loop (once per node)
        f16x8 lo = hw1v[2 * (size_t)i];
        f16x8 hi = hw1v[2 * (size_t)i + 1];
#pragma unroll
        for (int d = 0; d < 8; ++d) {
            a[d]     += (float)lo[d];
            a[8 + d] += (float)hi[d];
        }
    }
    // butterfly merge across the quad
#pragma unroll
    for (int d = 0; d < 16; ++d) a[d] += __shfl_xor(a[d], 1, 4);
#pragma unroll
    for (int d = 0; d < 16; ++d) a[d] += __shfl_xor(a[d], 2, 4);
    // fused GEMM2: lane j computes output dims 2j, 2j+1
    float o0 = 0.f, o1 = 0.f;
#pragma unroll
    for (int k = 0; k < 16; ++k) {
        float hv = di * a[k] + sb[k];
        o0 += hv * sW[k * 8 + 2 * j];
        o1 += hv * sW[k * 8 + 2 * j + 1];
    }
    f16x2 ho = {(_Float16)(di * o0), (_Float16)(di * o1)};
    *(f16x2*)&hw2h[(size_t)i * 8 + 2 * j] = ho;   // 4B store, 16B/node across quad
}

// layer-2 (exact R5): 4 lanes/node, 8-dim accumulator, prefetch + masked
// final chunk, butterfly merge, Wl dot + sigmoid.
__global__ __launch_bounds__(256) void k_agg2c(const int* __restrict__ rowstart,
                                               const int* __restrict__ rowend,
                                               const int* __restrict__ csr_src,
                                               const f16x8* __restrict__ hw2v,
                                               const float* __restrict__ Wl,
                                               const float* __restrict__ b2,
                                               const float* __restrict__ bl,
                                               float* __restrict__ z, int N) {
    __shared__ float sW[8], sb[8], sbl;
    int t = threadIdx.x;
    if (t < 8) { sW[t] = Wl[t]; sb[t] = b2[t]; }
    if (t == 0) sbl = bl[0];
    __syncthreads();
    int q = t >> 2, j = t & 3;
    int i = blockIdx.x * 64 + q;
    if (i >= N) return;
    int beg = rowstart[i], end = rowend[i];
    int deg = end - beg;
    float di = rsqrtf((float)(deg + 1));
    float a[8];
#pragma unroll
    for (int d = 0; d < 8; ++d) a[d] = 0.f;
    int nfull = deg >> 4;
    int base0 = beg + 4 * j;
    int s4[4];
    if (nfull > 0) {
#pragma unroll
        for (int m = 0; m < 4; ++m) s4[m] = csr_src[base0 + m];
    }
    for (int ch = 0; ch < nfull; ++ch) {
        f16x8 gv[4];
#pragma unroll
        for (int m = 0; m < 4; ++m) gv[m] = hw2v[(size_t)s4[m]];
        int sn[4];
        if (ch + 1 < nfull) {
#pragma unroll
            for (int m = 0; m < 4; ++m) sn[m] = csr_src[base0 + (ch + 1) * 16 + m];
        }
#pragma unroll
        for (int m = 0; m < 4; ++m)
#pragma unroll
            for (int d = 0; d < 8; ++d) a[d] += (float)gv[m][d];
        if (ch + 1 < nfull) {
#pragma unroll
            for (int m = 0; m < 4; ++m) s4[m] = sn[m];
        }
    }
    if (deg & 15) {
        int cb = beg + nfull * 16 + 4 * j;
        int   sr[4];
        float wr[4];
#pragma unroll
        for (int m = 0; m < 4; ++m) {
            int c = cb + m;
            bool ok = c < end;
            sr[m] = ok ? csr_src[c] : i;
            wr[m] = ok ? 1.f : 0.f;
        }
        f16x8 gv[4];
#pragma unroll
        for (int m = 0; m < 4; ++m) gv[m] = hw2v[(size_t)sr[m]];
#pragma unroll
        for (int m = 0; m < 4; ++m)
#pragma unroll
            for (int d = 0; d < 8; ++d) a[d] += wr[m] * (float)gv[m][d];
    }
    if (j == 0) {
        f16x8 self = hw2v[(size_t)i];
#pragma unroll
        for (int d = 0; d < 8; ++d) a[d] += (float)self[d];
    }
#pragma unroll
    for (int d = 0; d < 8; ++d) a[d] += __shfl_xor(a[d], 1, 4);
#pragma unroll
    for (int d = 0; d < 8; ++d) a[d] += __shfl_xor(a[d], 2, 4);
    if (j == 0) {
        float v = 0.f;
#pragma unroll
        for (int d = 0; d < 8; ++d) {
            float h = di * a[d] + sb[d];
            v += h * sW[d];
        }
        z[i] = 1.f / (1.f + __expf(-(v + sbl)));
    }
}

__global__ __launch_bounds__(256) void k_pred(const int2* __restrict__ pe2,
                                              const float* __restrict__ z,
                                              float* __restrict__ out, int P) {
    int p = blockIdx.x * 256 + threadIdx.x;
    if (p < P) {
        int2 e = pe2[p];
        out[p] = z[e.x] * z[e.y];
    }
}

// ---------------- launch ----------------

extern "C" void kernel_launch(void* const* d_in, const int* in_sizes, int n_in,
                              void* d_out, int out_size, void* d_ws, size_t ws_size,
                              hipStream_t stream) {
    const float* x  = (const float*)d_in[0];
    const int*   ei = (const int*)d_in[1];
    const int*   pe = (const int*)d_in[2];
    const float* W1 = (const float*)d_in[3];
    const float* b1 = (const float*)d_in[4];
    const float* W2 = (const float*)d_in[5];
    const float* b2 = (const float*)d_in[6];
    const float* Wl = (const float*)d_in[7];
    const float* bl = (const float*)d_in[8];
    float* out = (float*)d_out;

    const int N = in_sizes[0] / 128;
    const int E = in_sizes[1] / 2;
    const int P = in_sizes[2] / 2;
    const int NBUK = (N + BUCK - 1) >> BSHIFT;   // 782 for N=100000

    const int* src = ei;
    const int* dst = ei + E;

    // workspace (4B words), ~45 MB (binned/csr footprint identical to R5:
    // 782*6144 == 391*12288):
    float*  ws   = (float*)d_ws;
    float*  dinv = ws;                               // N
    __half* hw1h = (__half*)(ws + (size_t)N);        // 16N halves = 8N words (16B-aligned)
    __half* hw2h = (__half*)(ws + (size_t)9 * N);    // 8N halves = 4N words
    float*  z    = ws + (size_t)13 * N;              // N
    int* rowstart = (int*)(ws + (size_t)14 * N);     // N
    int* rowend   = rowstart + N;                    // N
    int* bcursor  = rowend + N;                      // 1024 slots
    int* binned   = bcursor + 1024;                  // NBUK*CAP (sparse)
    int* csr_src  = binned + (size_t)NBUK * CAP;     // NBUK*CAP (sparse)

    const int B = 256;

    k_curinit<<<4, B, 0, stream>>>(bcursor, 1024);
    k_binscatter<<<(E + TILE - 1) / TILE, 512, 0, stream>>>(src, dst, bcursor, binned, E, NBUK);
    k_sortbucket<<<NBUK, 512, 0, stream>>>(bcursor, binned, csr_src, rowstart, rowend, dinv, N);
    k_gemm1<<<(N + 63) / 64, B, 0, stream>>>(x, W1, dinv, hw1h, N);
    k_agg1c<<<(N + 63) / 64, B, 0, stream>>>(rowstart, rowend, csr_src,
                                             (const f16x8*)hw1h, W2, b1, hw2h, N);
    k_agg2c<<<(N + 63) / 64, B, 0, stream>>>(rowstart, rowend, csr_src,
                                             (const f16x8*)hw2h, Wl, b2, bl, z, N);
    k_pred<<<(P + B - 1) / B, B, 0, stream>>>((const int2*)pe, z, out, P);
}

// Round 10
// 196.088 us; speedup vs baseline: 1.1747x; 1.1747x over previous
//
#include <hip/hip_runtime.h>
#include <hip/hip_fp16.h>
#include <math.h>

// Fixed-capacity bucketed CSR build (per-tile LDS counting sort -> coalesced
// bucket writes), then node-parallel coalesced gather aggregation with fp16
// gather tables (hw1h 3.2 MB, hw2h 1.6 MB -> L2-resident).
// gemm1 (x@W1, dinv-prescaled) via MFMA f32_16x16x32_f16.
// R1: wave-shuffle scans. R3: quad-split agg. R5: masked tails + idx prefetch
//     (BEST: 206.9 us).
// R6 (REVERTED): LDS-atomic agg 8x slower. R7/R8 (REVERTED): neutral.
// R9 (REVERTED): smaller binscatter tiles halved bucket-run length ->
//     2.5x write amplification (WRITE_SIZE 33 MB for 13 MB payload), +20 us.
// R10: R5 + LDS-staged sortbucket scatter: sort into sp[CAP] in LDS, then
//     coalesced linear copy-out (binscatter's own pattern). Removes the
//     3.2M scattered 4B global writes (same partial-line pathology R9
//     exposed in binscatter).
#define BSHIFT 8
#define BUCK   256
#define TILE   8192     // edges per scatter workgroup (1024 threads, 8 edges/thread)
#define CAP    12288    // bucket capacity; mean 8184, sigma 90 -> 45 sigma headroom

typedef _Float16 f16x2 __attribute__((ext_vector_type(2)));
typedef _Float16 f16x4 __attribute__((ext_vector_type(4)));
typedef _Float16 f16x8 __attribute__((ext_vector_type(8)));
typedef float    f32x4 __attribute__((ext_vector_type(4)));

// ---------------- CSR build ----------------

__global__ __launch_bounds__(256) void k_curinit(int* __restrict__ bcursor, int nbuk) {
    int b = blockIdx.x * 256 + threadIdx.x;
    if (b < nbuk) bcursor[b] = b * CAP;
}

// tile scatter with full per-tile LDS counting sort by bucket, so the global
// binned[] writes are lane-consecutive (coalesced bursts per bucket run).
// packed edge = (dst&255)<<17 | src   (src < 2^17)
__global__ __launch_bounds__(1024) void k_binscatter(const int* __restrict__ src,
                                                     const int* __restrict__ dst,
                                                     int* __restrict__ bcursor,
                                                     int* __restrict__ binned, int E, int nbuk) {
    __shared__ int            payload[TILE];   // 32 KB
    __shared__ unsigned short bid16[TILE];     // 16 KB
    __shared__ int cnt[512];                   // hist -> local cursor
    __shared__ int lstart[512];                // exclusive scan (local base)
    __shared__ int gbase[512];                 // reserved global base
    __shared__ int wsum[8];
    int t = threadIdx.x;
    int tile0 = blockIdx.x * TILE;
    int tileE = min(TILE, E - tile0);
    if (t < 512) cnt[t] = 0;
    __syncthreads();
    // load 8 edges/thread (vectorized when full)
    int d[8], s[8];
    int base = t * 8;
    if (base + 8 <= tileE) {
        const int4* d4 = (const int4*)(dst + tile0 + base);
        const int4* s4 = (const int4*)(src + tile0 + base);
        int4 da = d4[0], db = d4[1];
        int4 sa = s4[0], sb = s4[1];
        d[0] = da.x; d[1] = da.y; d[2] = da.z; d[3] = da.w;
        d[4] = db.x; d[5] = db.y; d[6] = db.z; d[7] = db.w;
        s[0] = sa.x; s[1] = sa.y; s[2] = sa.z; s[3] = sa.w;
        s[4] = sb.x; s[5] = sb.y; s[6] = sb.z; s[7] = sb.w;
    } else {
#pragma unroll
        for (int q = 0; q < 8; ++q) {
            int idx = base + q;
            if (idx < tileE) { d[q] = dst[tile0 + idx]; s[q] = src[tile0 + idx]; }
            else d[q] = -1;
        }
    }
#pragma unroll
    for (int q = 0; q < 8; ++q)
        if (d[q] >= 0) atomicAdd(&cnt[d[q] >> BSHIFT], 1);
    __syncthreads();
    // wave-shuffle exclusive scan over cnt[512]: 8 full waves scan 64 each,
    // thread 0 combines wave sums. 4 barriers total.
    int c = 0, ex = 0;
    if (t < 512) {
        c = cnt[t];
        int v = c;
#pragma unroll
        for (int off = 1; off < 64; off <<= 1) {
            int u = __shfl_up(v, off, 64);
            if ((t & 63) >= off) v += u;
        }
        if ((t & 63) == 63) wsum[t >> 6] = v;
        ex = v - c;
    }
    __syncthreads();
    if (t == 0) {
        int run = 0;
#pragma unroll
        for (int w = 0; w < 8; ++w) { int u = wsum[w]; wsum[w] = run; run += u; }
    }
    __syncthreads();
    if (t < 512) {
        ex += wsum[t >> 6];
        gbase[t] = c ? atomicAdd(&bcursor[t], c) : 0;   // reserve global run
        lstart[t] = ex;                                  // local base
        cnt[t] = ex;                                     // local cursor
    }
    __syncthreads();
    // LDS scatter: sort tile's edges by bucket
#pragma unroll
    for (int q = 0; q < 8; ++q) {
        if (d[q] >= 0) {
            int b = d[q] >> BSHIFT;
            int lp = atomicAdd(&cnt[b], 1);
            payload[lp] = ((d[q] & (BUCK - 1)) << 17) | s[q];
            bid16[lp] = (unsigned short)b;
        }
    }
    __syncthreads();
    // coalesced copy-out: consecutive k -> consecutive global addresses
    for (int k = t; k < tileE; k += 1024) {
        int b = bid16[k];
        int ga = gbase[b] + (k - lstart[b]);
        if (ga < (b + 1) * CAP)                          // overflow guard (45 sigma)
            binned[ga] = payload[k];
    }
}

// per-bucket counting sort -> csr_src (dst-sorted, sparse layout), rowstart/
// rowend, dinv. R10: scatter into LDS sp[CAP], then coalesced copy-out
// (was: scattered 4B global writes -> partial-line write amplification).
__global__ __launch_bounds__(1024) void k_sortbucket(const int* __restrict__ bcursor,
                                                     const int* __restrict__ binned,
                                                     int* __restrict__ csr_src,
                                                     int* __restrict__ rowstart,
                                                     int* __restrict__ rowend,
                                                     float* __restrict__ dinv, int N) {
    __shared__ int sp[CAP];          // 48 KB sorted payload stage
    __shared__ int cnt[BUCK];
    __shared__ int cur[BUCK];
    __shared__ int wsum[4];
    int b = blockIdx.x, t = threadIdx.x;
    if (t < BUCK) cnt[t] = 0;
    __syncthreads();
    int beg = b * CAP;
    int end = min(bcursor[b], beg + CAP);
    int tot = end - beg;
    int v[12];
#pragma unroll
    for (int q = 0; q < 12; ++q) {
        int e = beg + q * 1024 + t;
        v[q] = (e < end) ? binned[e] : -1;
    }
#pragma unroll
    for (int q = 0; q < 12; ++q)
        if (v[q] >= 0) atomicAdd(&cnt[v[q] >> 17], 1);
    __syncthreads();
    // wave-shuffle exclusive scan over cnt[256] (4 full waves + combine)
    int c = 0, ex = 0;
    if (t < BUCK) {
        c = cnt[t];
        int s = c;
#pragma unroll
        for (int off = 1; off < 64; off <<= 1) {
            int u = __shfl_up(s, off, 64);
            if ((t & 63) >= off) s += u;
        }
        if ((t & 63) == 63) wsum[t >> 6] = s;
        ex = s - c;
    }
    __syncthreads();
    if (t == 0) {
        int run = 0;
#pragma unroll
        for (int w = 0; w < 4; ++w) { int u = wsum[w]; wsum[w] = run; run += u; }
    }
    __syncthreads();
    if (t < BUCK) {
        ex += wsum[t >> 6];
        cur[t] = ex;
        int node = b * BUCK + t;
        if (node < N) {
            rowstart[node] = beg + ex;
            rowend[node]   = beg + ex + c;
            dinv[node] = rsqrtf((float)(c + 1));   // +1 self loop
        }
    }
    __syncthreads();
#pragma unroll
    for (int q = 0; q < 12; ++q) {
        if (v[q] >= 0) {
            int pos = atomicAdd(&cur[v[q] >> 17], 1);
            sp[pos] = v[q] & 0x1FFFF;              // LDS scatter (pos < tot <= CAP)
        }
    }
    __syncthreads();
    for (int k = t; k < tot; k += 1024)            // coalesced copy-out
        csr_src[beg + k] = sp[k];
}

// ---------------- layer compute ----------------

// hw1h[i,:] = fp16( dinv[i] * (x[i,:] @ W1) ) via MFMA 16x16x32 f16.
__global__ __launch_bounds__(256) void k_gemm1(const float* __restrict__ x,
                                               const float* __restrict__ W1,
                                               const float* __restrict__ dinv,
                                               __half* __restrict__ hw1h, int N) {
    __shared__ _Float16 sX[64 * 136];   // x tile fp16, row pad 136
    __shared__ _Float16 sW[16 * 136];   // W1^T fp16
    __shared__ float    sDi[64];
    __shared__ _Float16 sOut[64 * 16];
    int t = threadIdx.x;
    int row0 = blockIdx.x * 64;
    for (int e = t; e < 2048; e += 256) {
        int n = e & 15, k = e >> 4;
        sW[n * 136 + k] = (_Float16)W1[k * 16 + n];
    }
    const float4* x4 = (const float4*)x;
#pragma unroll
    for (int q = 0; q < 8; ++q) {
        int e = q * 256 + t;
        int r = e >> 5, c4 = e & 31;
        int gr = row0 + r;
        float4 v = (gr < N) ? x4[(size_t)gr * 32 + c4] : make_float4(0.f, 0.f, 0.f, 0.f);
        f16x4 hv = {(_Float16)v.x, (_Float16)v.y, (_Float16)v.z, (_Float16)v.w};
        *(f16x4*)&sX[r * 136 + c4 * 4] = hv;   // one ds_write_b64 (8B-aligned)
    }
    if (t < 64) sDi[t] = (row0 + t < N) ? dinv[row0 + t] : 0.f;
    __syncthreads();
    int w = t >> 6, l = t & 63;
    int m = l & 15, quad = l >> 4;
    f32x4 acc = {0.f, 0.f, 0.f, 0.f};
#pragma unroll
    for (int kc = 0; kc < 4; ++kc) {
        f16x8 a = *(const f16x8*)&sX[(w * 16 + m) * 136 + kc * 32 + quad * 8];
        f16x8 b = *(const f16x8*)&sW[m * 136 + kc * 32 + quad * 8];
        acc = __builtin_amdgcn_mfma_f32_16x16x32_f16(a, b, acc, 0, 0, 0);
    }
#pragma unroll
    for (int r = 0; r < 4; ++r) {
        int nl = w * 16 + quad * 4 + r;
        sOut[nl * 16 + m] = (_Float16)(acc[r] * sDi[nl]);
    }
    __syncthreads();
    int nn = t >> 2, ch = t & 3;
    int gn = row0 + nn;
    if (gn < N)
        *(float2*)&hw1h[(size_t)gn * 16 + ch * 4] = *(float2*)&sOut[nn * 16 + ch * 4];
}

// layer-1 (exact R5): 4 lanes/node, quad-split edge list, 2-deep index
// prefetch, masked full-width final chunk, shfl_xor butterfly merge, fused
// register GEMM2 (lane j -> out dims 2j,2j+1) -> hw2h (fp16, dinv-prescaled).
__global__ __launch_bounds__(256) void k_agg1c(const int* __restrict__ rowstart,
                                               const int* __restrict__ rowend,
                                               const int* __restrict__ csr_src,
                                               const f16x8* __restrict__ hw1v,
                                               const float* __restrict__ W2,
                                               const float* __restrict__ b1,
                                               __half* __restrict__ hw2h, int N) {
    __shared__ float sW[128], sb[16];
    int t = threadIdx.x;
    if (t < 128) sW[t] = W2[t];
    if (t < 16)  sb[t] = b1[t];
    __syncthreads();
    int q = t >> 2, j = t & 3;
    int i = blockIdx.x * 64 + q;
    if (i >= N) return;
    int beg = rowstart[i], end = rowend[i];
    int deg = end - beg;
    float di = rsqrtf((float)(deg + 1));
    float a[16];
#pragma unroll
    for (int d = 0; d < 16; ++d) a[d] = 0.f;
    int nfull = deg >> 4;
    int base0 = beg + 4 * j;
    int s4[4];
    if (nfull > 0) {
#pragma unroll
        for (int m = 0; m < 4; ++m) s4[m] = csr_src[base0 + m];
    }
    for (int ch = 0; ch < nfull; ++ch) {
        f16x8 lo[4], hi[4];
#pragma unroll
        for (int m = 0; m < 4; ++m) {
            lo[m] = hw1v[2 * (size_t)s4[m]];
            hi[m] = hw1v[2 * (size_t)s4[m] + 1];
        }
        int sn[4];
        if (ch + 1 < nfull) {      // prefetch next chunk's indices under gathers
#pragma unroll
            for (int m = 0; m < 4; ++m) sn[m] = csr_src[base0 + (ch + 1) * 16 + m];
        }
#pragma unroll
        for (int m = 0; m < 4; ++m) {
#pragma unroll
            for (int d = 0; d < 8; ++d) {
                a[d]     += (float)lo[m][d];
                a[8 + d] += (float)hi[m][d];
            }
        }
        if (ch + 1 < nfull) {
#pragma unroll
            for (int m = 0; m < 4; ++m) s4[m] = sn[m];
        }
    }
    if (deg & 15) {                // masked full-width final chunk
        int cb = beg + nfull * 16 + 4 * j;
        int   sr[4];
        float wr[4];
#pragma unroll
        for (int m = 0; m < 4; ++m) {
            int c = cb + m;
            bool ok = c < end;
            sr[m] = ok ? csr_src[c] : i;   // dummy = self row (hot line), weight 0
            wr[m] = ok ? 1.f : 0.f;
        }
        f16x8 lo[4], hi[4];
#pragma unroll
        for (int m = 0; m < 4; ++m) {
            lo[m] = hw1v[2 * (size_t)sr[m]];
            hi[m] = hw1v[2 * (size_t)sr[m] + 1];
        }
#pragma unroll
        for (int m = 0; m < 4; ++m) {
#pragma unroll
            for (int d = 0; d < 8; ++d) {
                a[d]     += wr[m] * (float)lo[m][d];
                a[8 + d] += wr[m] * (float)hi[m][d];
            }
        }
    }
    if (j == 0) {   // self loop (once per node)
        f16x8 lo = hw1v[2 * (size_t)i];
        f16x8 hi = hw1v[2 * (size_t)i + 1];
#pragma unroll
        for (int d = 0; d < 8; ++d) {
            a[d]     += (float)lo[d];
            a[8 + d] += (float)hi[d];
        }
    }
    // butterfly merge across the quad
#pragma unroll
    for (int d = 0; d < 16; ++d) a[d] += __shfl_xor(a[d], 1, 4);
#pragma unroll
    for (int d = 0; d < 16; ++d) a[d] += __shfl_xor(a[d], 2, 4);
    // fused GEMM2: lane j computes output dims 2j, 2j+1
    float o0 = 0.f, o1 = 0.f;
#pragma unroll
    for (int k = 0; k < 16; ++k) {
        float hv = di * a[k] + sb[k];
        o0 += hv * sW[k * 8 + 2 * j];
        o1 += hv * sW[k * 8 + 2 * j + 1];
    }
    f16x2 ho = {(_Float16)(di * o0), (_Float16)(di * o1)};
    *(f16x2*)&hw2h[(size_t)i * 8 + 2 * j] = ho;   // 4B store, 16B/node across quad
}

// layer-2 (exact R5): 4 lanes/node, 8-dim accumulator, prefetch + masked
// final chunk, butterfly merge, Wl dot + sigmoid.
__global__ __launch_bounds__(256) void k_agg2c(const int* __restrict__ rowstart,
                                               const int* __restrict__ rowend,
                                               const int* __restrict__ csr_src,
                                               const f16x8* __restrict__ hw2v,
                                               const float* __restrict__ Wl,
                                               const float* __restrict__ b2,
                                               const float* __restrict__ bl,
                                               float* __restrict__ z, int N) {
    __shared__ float sW[8], sb[8], sbl;
    int t = threadIdx.x;
    if (t < 8) { sW[t] = Wl[t]; sb[t] = b2[t]; }
    if (t == 0) sbl = bl[0];
    __syncthreads();
    int q = t >> 2, j = t & 3;
    int i = blockIdx.x * 64 + q;
    if (i >= N) return;
    int beg = rowstart[i], end = rowend[i];
    int deg = end - beg;
    float di = rsqrtf((float)(deg + 1));
    float a[8];
#pragma unroll
    for (int d = 0; d < 8; ++d) a[d] = 0.f;
    int nfull = deg >> 4;
    int base0 = beg + 4 * j;
    int s4[4];
    if (nfull > 0) {
#pragma unroll
        for (int m = 0; m < 4; ++m) s4[m] = csr_src[base0 + m];
    }
    for (int ch = 0; ch < nfull; ++ch) {
        f16x8 gv[4];
#pragma unroll
        for (int m = 0; m < 4; ++m) gv[m] = hw2v[(size_t)s4[m]];
        int sn[4];
        if (ch + 1 < nfull) {
#pragma unroll
            for (int m = 0; m < 4; ++m) sn[m] = csr_src[base0 + (ch + 1) * 16 + m];
        }
#pragma unroll
        for (int m = 0; m < 4; ++m)
#pragma unroll
            for (int d = 0; d < 8; ++d) a[d] += (float)gv[m][d];
        if (ch + 1 < nfull) {
#pragma unroll
            for (int m = 0; m < 4; ++m) s4[m] = sn[m];
        }
    }
    if (deg & 15) {
        int cb = beg + nfull * 16 + 4 * j;
        int   sr[4];
        float wr[4];
#pragma unroll
        for (int m = 0; m < 4; ++m) {
            int c = cb + m;
            bool ok = c < end;
            sr[m] = ok ? csr_src[c] : i;
            wr[m] = ok ? 1.f : 0.f;
        }
        f16x8 gv[4];
#pragma unroll
        for (int m = 0; m < 4; ++m) gv[m] = hw2v[(size_t)sr[m]];
#pragma unroll
        for (int m = 0; m < 4; ++m)
#pragma unroll
            for (int d = 0; d < 8; ++d) a[d] += wr[m] * (float)gv[m][d];
    }
    if (j == 0) {
        f16x8 self = hw2v[(size_t)i];
#pragma unroll
        for (int d = 0; d < 8; ++d) a[d] += (float)self[d];
    }
#pragma unroll
    for (int d = 0; d < 8; ++d) a[d] += __shfl_xor(a[d], 1, 4);
#pragma unroll
    for (int d = 0; d < 8; ++d) a[d] += __shfl_xor(a[d], 2, 4);
    if (j == 0) {
        float v = 0.f;
#pragma unroll
        for (int d = 0; d < 8; ++d) {
            float h = di * a[d] + sb[d];
            v += h * sW[d];
        }
        z[i] = 1.f / (1.f + __expf(-(v + sbl)));
    }
}

__global__ __launch_bounds__(256) void k_pred(const int2* __restrict__ pe2,
                                              const float* __restrict__ z,
                                              float* __restrict__ out, int P) {
    int p = blockIdx.x * 256 + threadIdx.x;
    if (p < P) {
        int2 e = pe2[p];
        out[p] = z[e.x] * z[e.y];
    }
}

// ---------------- launch ----------------

extern "C" void kernel_launch(void* const* d_in, const int* in_sizes, int n_in,
                              void* d_out, int out_size, void* d_ws, size_t ws_size,
                              hipStream_t stream) {
    const float* x  = (const float*)d_in[0];
    const int*   ei = (const int*)d_in[1];
    const int*   pe = (const int*)d_in[2];
    const float* W1 = (const float*)d_in[3];
    const float* b1 = (const float*)d_in[4];
    const float* W2 = (const float*)d_in[5];
    const float* b2 = (const float*)d_in[6];
    const float* Wl = (const float*)d_in[7];
    const float* bl = (const float*)d_in[8];
    float* out = (float*)d_out;

    const int N = in_sizes[0] / 128;
    const int E = in_sizes[1] / 2;
    const int P = in_sizes[2] / 2;
    const int NBUK = (N + BUCK - 1) >> BSHIFT;   // 391 for N=100000

    const int* src = ei;
    const int* dst = ei + E;

    // workspace (4B words), ~45 MB:
    float*  ws   = (float*)d_ws;
    float*  dinv = ws;                               // N
    __half* hw1h = (__half*)(ws + (size_t)N);        // 16N halves = 8N words (16B-aligned)
    __half* hw2h = (__half*)(ws + (size_t)9 * N);    // 8N halves = 4N words
    float*  z    = ws + (size_t)13 * N;              // N
    int* rowstart = (int*)(ws + (size_t)14 * N);     // N
    int* rowend   = rowstart + N;                    // N
    int* bcursor  = rowend + N;                      // NBUK
    int* binned   = bcursor + 512;                   // NBUK*CAP (sparse)
    int* csr_src  = binned + (size_t)NBUK * CAP;     // NBUK*CAP (sparse)

    const int B = 256;

    k_curinit<<<(NBUK + B - 1) / B, B, 0, stream>>>(bcursor, NBUK);
    k_binscatter<<<(E + TILE - 1) / TILE, 1024, 0, stream>>>(src, dst, bcursor, binned, E, NBUK);
    k_sortbucket<<<NBUK, 1024, 0, stream>>>(bcursor, binned, csr_src, rowstart, rowend, dinv, N);
    k_gemm1<<<(N + 63) / 64, B, 0, stream>>>(x, W1, dinv, hw1h, N);
    k_agg1c<<<(N + 63) / 64, B, 0, stream>>>(rowstart, rowend, csr_src,
                                             (const f16x8*)hw1h, W2, b1, hw2h, N);
    k_agg2c<<<(N + 63) / 64, B, 0, stream>>>(rowstart, rowend, csr_src,
                                             (const f16x8*)hw2h, Wl, b2, bl, z, N);
    k_pred<<<(P + B - 1) / B, B, 0, stream>>>((const int2*)pe, z, out, P);
}

// Round 11
// 193.570 us; speedup vs baseline: 1.1900x; 1.0130x over previous
//
#include <hip/hip_runtime.h>
#include <hip/hip_fp16.h>
#include <math.h>

// Fixed-capacity bucketed CSR build (per-tile LDS counting sort -> coalesced
// bucket writes), then node-parallel coalesced gather aggregation with fp16
// gather tables (hw1h 3.2 MB, hw2h 1.6 MB -> L2-resident).
// gemm1 (x@W1, dinv-prescaled) via MFMA f32_16x16x32_f16.
// R1: wave-shuffle scans. R3: quad-split agg. R5: masked tails + idx prefetch.
// R10: LDS-staged sortbucket scatter (WIN, -10.8 us: partial-line write fix).
// R11: RANK CAPTURE — the histogram atomicAdd's return value IS the edge's
//     rank within its bucket; scatter position = lstart[b] + rank. Deletes
//     the second LDS-atomic pass in BOTH binscatter and sortbucket (12.8M ->
//     6.4M atomic lane-ops pipeline-wide; binscatter is atomic-throughput
//     bound at ~4 cy/lane-op).
#define BSHIFT 8
#define BUCK   256
#define TILE   8192     // edges per scatter workgroup (1024 threads, 8 edges/thread)
#define CAP    12288    // bucket capacity; mean 8184, sigma 90 -> 45 sigma headroom

typedef _Float16 f16x2 __attribute__((ext_vector_type(2)));
typedef _Float16 f16x4 __attribute__((ext_vector_type(4)));
typedef _Float16 f16x8 __attribute__((ext_vector_type(8)));
typedef float    f32x4 __attribute__((ext_vector_type(4)));

// ---------------- CSR build ----------------

__global__ __launch_bounds__(256) void k_curinit(int* __restrict__ bcursor, int nbuk) {
    int b = blockIdx.x * 256 + threadIdx.x;
    if (b < nbuk) bcursor[b] = b * CAP;
}

// tile scatter with full per-tile LDS counting sort by bucket, so the global
// binned[] writes are lane-consecutive (coalesced bursts per bucket run).
// packed edge = (dst&255)<<17 | src   (src < 2^17)
// R11: single atomic pass — histogram atomicAdd returns per-edge rank.
__global__ __launch_bounds__(1024) void k_binscatter(const int* __restrict__ src,
                                                     const int* __restrict__ dst,
                                                     int* __restrict__ bcursor,
                                                     int* __restrict__ binned, int E, int nbuk) {
    __shared__ int            payload[TILE];   // 32 KB
    __shared__ unsigned short bid16[TILE];     // 16 KB
    __shared__ int cnt[512];                   // histogram
    __shared__ int lstart[512];                // exclusive scan (local base)
    __shared__ int gbase[512];                 // reserved global base
    __shared__ int wsum[8];
    int t = threadIdx.x;
    int tile0 = blockIdx.x * TILE;
    int tileE = min(TILE, E - tile0);
    if (t < 512) cnt[t] = 0;
    __syncthreads();
    // load 8 edges/thread (vectorized when full)
    int d[8], s[8];
    int base = t * 8;
    if (base + 8 <= tileE) {
        const int4* d4 = (const int4*)(dst + tile0 + base);
        const int4* s4 = (const int4*)(src + tile0 + base);
        int4 da = d4[0], db = d4[1];
        int4 sa = s4[0], sb = s4[1];
        d[0] = da.x; d[1] = da.y; d[2] = da.z; d[3] = da.w;
        d[4] = db.x; d[5] = db.y; d[6] = db.z; d[7] = db.w;
        s[0] = sa.x; s[1] = sa.y; s[2] = sa.z; s[3] = sa.w;
        s[4] = sb.x; s[5] = sb.y; s[6] = sb.z; s[7] = sb.w;
    } else {
#pragma unroll
        for (int q = 0; q < 8; ++q) {
            int idx = base + q;
            if (idx < tileE) { d[q] = dst[tile0 + idx]; s[q] = src[tile0 + idx]; }
            else d[q] = -1;
        }
    }
    int rank[8];                               // rank within bucket (free!)
#pragma unroll
    for (int q = 0; q < 8; ++q)
        if (d[q] >= 0) rank[q] = atomicAdd(&cnt[d[q] >> BSHIFT], 1);
    __syncthreads();
    // wave-shuffle exclusive scan over cnt[512]: 8 full waves scan 64 each,
    // thread 0 combines wave sums.
    int c = 0, ex = 0;
    if (t < 512) {
        c = cnt[t];
        int v = c;
#pragma unroll
        for (int off = 1; off < 64; off <<= 1) {
            int u = __shfl_up(v, off, 64);
            if ((t & 63) >= off) v += u;
        }
        if ((t & 63) == 63) wsum[t >> 6] = v;
        ex = v - c;
    }
    __syncthreads();
    if (t == 0) {
        int run = 0;
#pragma unroll
        for (int w = 0; w < 8; ++w) { int u = wsum[w]; wsum[w] = run; run += u; }
    }
    __syncthreads();
    if (t < 512) {
        ex += wsum[t >> 6];
        gbase[t] = c ? atomicAdd(&bcursor[t], c) : 0;   // reserve global run
        lstart[t] = ex;                                  // local base
    }
    __syncthreads();
    // LDS scatter WITHOUT atomics: position = lstart[b] + rank
#pragma unroll
    for (int q = 0; q < 8; ++q) {
        if (d[q] >= 0) {
            int b = d[q] >> BSHIFT;
            int lp = lstart[b] + rank[q];
            payload[lp] = ((d[q] & (BUCK - 1)) << 17) | s[q];
            bid16[lp] = (unsigned short)b;
        }
    }
    __syncthreads();
    // coalesced copy-out: consecutive k -> consecutive global addresses
    for (int k = t; k < tileE; k += 1024) {
        int b = bid16[k];
        int ga = gbase[b] + (k - lstart[b]);
        if (ga < (b + 1) * CAP)                          // overflow guard (45 sigma)
            binned[ga] = payload[k];
    }
}

// per-bucket counting sort -> csr_src (dst-sorted, sparse layout), rowstart/
// rowend, dinv. R10: LDS-staged scatter + coalesced copy-out. R11: rank
// capture in histogram -> atomic-free scatter.
__global__ __launch_bounds__(1024) void k_sortbucket(const int* __restrict__ bcursor,
                                                     const int* __restrict__ binned,
                                                     int* __restrict__ csr_src,
                                                     int* __restrict__ rowstart,
                                                     int* __restrict__ rowend,
                                                     float* __restrict__ dinv, int N) {
    __shared__ int sp[CAP];          // 48 KB sorted payload stage
    __shared__ int cnt[BUCK];
    __shared__ int excl[BUCK];
    __shared__ int wsum[4];
    int b = blockIdx.x, t = threadIdx.x;
    if (t < BUCK) cnt[t] = 0;
    __syncthreads();
    int beg = b * CAP;
    int end = min(bcursor[b], beg + CAP);
    int tot = end - beg;
    int v[12];
#pragma unroll
    for (int q = 0; q < 12; ++q) {
        int e = beg + q * 1024 + t;
        v[q] = (e < end) ? binned[e] : -1;
    }
    int rk[12];                      // rank within node (free from histogram)
#pragma unroll
    for (int q = 0; q < 12; ++q)
        if (v[q] >= 0) rk[q] = atomicAdd(&cnt[v[q] >> 17], 1);
    __syncthreads();
    // wave-shuffle exclusive scan over cnt[256] (4 full waves + combine)
    int c = 0, ex = 0;
    if (t < BUCK) {
        c = cnt[t];
        int s = c;
#pragma unroll
        for (int off = 1; off < 64; off <<= 1) {
            int u = __shfl_up(s, off, 64);
            if ((t & 63) >= off) s += u;
        }
        if ((t & 63) == 63) wsum[t >> 6] = s;
        ex = s - c;
    }
    __syncthreads();
    if (t == 0) {
        int run = 0;
#pragma unroll
        for (int w = 0; w < 4; ++w) { int u = wsum[w]; wsum[w] = run; run += u; }
    }
    __syncthreads();
    if (t < BUCK) {
        ex += wsum[t >> 6];
        excl[t] = ex;
        int node = b * BUCK + t;
        if (node < N) {
            rowstart[node] = beg + ex;
            rowend[node]   = beg + ex + c;
            dinv[node] = rsqrtf((float)(c + 1));   // +1 self loop
        }
    }
    __syncthreads();
    // LDS scatter WITHOUT atomics: pos = excl[node] + rank
#pragma unroll
    for (int q = 0; q < 12; ++q) {
        if (v[q] >= 0) {
            int pos = excl[v[q] >> 17] + rk[q];
            sp[pos] = v[q] & 0x1FFFF;              // pos < tot <= CAP
        }
    }
    __syncthreads();
    for (int k = t; k < tot; k += 1024)            // coalesced copy-out
        csr_src[beg + k] = sp[k];
}

// ---------------- layer compute ----------------

// hw1h[i,:] = fp16( dinv[i] * (x[i,:] @ W1) ) via MFMA 16x16x32 f16.
__global__ __launch_bounds__(256) void k_gemm1(const float* __restrict__ x,
                                               const float* __restrict__ W1,
                                               const float* __restrict__ dinv,
                                               __half* __restrict__ hw1h, int N) {
    __shared__ _Float16 sX[64 * 136];   // x tile fp16, row pad 136
    __shared__ _Float16 sW[16 * 136];   // W1^T fp16
    __shared__ float    sDi[64];
    __shared__ _Float16 sOut[64 * 16];
    int t = threadIdx.x;
    int row0 = blockIdx.x * 64;
    for (int e = t; e < 2048; e += 256) {
        int n = e & 15, k = e >> 4;
        sW[n * 136 + k] = (_Float16)W1[k * 16 + n];
    }
    const float4* x4 = (const float4*)x;
#pragma unroll
    for (int q = 0; q < 8; ++q) {
        int e = q * 256 + t;
        int r = e >> 5, c4 = e & 31;
        int gr = row0 + r;
        float4 v = (gr < N) ? x4[(size_t)gr * 32 + c4] : make_float4(0.f, 0.f, 0.f, 0.f);
        f16x4 hv = {(_Float16)v.x, (_Float16)v.y, (_Float16)v.z, (_Float16)v.w};
        *(f16x4*)&sX[r * 136 + c4 * 4] = hv;   // one ds_write_b64 (8B-aligned)
    }
    if (t < 64) sDi[t] = (row0 + t < N) ? dinv[row0 + t] : 0.f;
    __syncthreads();
    int w = t >> 6, l = t & 63;
    int m = l & 15, quad = l >> 4;
    f32x4 acc = {0.f, 0.f, 0.f, 0.f};
#pragma unroll
    for (int kc = 0; kc < 4; ++kc) {
        f16x8 a = *(const f16x8*)&sX[(w * 16 + m) * 136 + kc * 32 + quad * 8];
        f16x8 b = *(const f16x8*)&sW[m * 136 + kc * 32 + quad * 8];
        acc = __builtin_amdgcn_mfma_f32_16x16x32_f16(a, b, acc, 0, 0, 0);
    }
#pragma unroll
    for (int r = 0; r < 4; ++r) {
        int nl = w * 16 + quad * 4 + r;
        sOut[nl * 16 + m] = (_Float16)(acc[r] * sDi[nl]);
    }
    __syncthreads();
    int nn = t >> 2, ch = t & 3;
    int gn = row0 + nn;
    if (gn < N)
        *(float2*)&hw1h[(size_t)gn * 16 + ch * 4] = *(float2*)&sOut[nn * 16 + ch * 4];
}

// layer-1 (exact R5): 4 lanes/node, quad-split edge list, 2-deep index
// prefetch, masked full-width final chunk, shfl_xor butterfly merge, fused
// register GEMM2 (lane j -> out dims 2j,2j+1) -> hw2h (fp16, dinv-prescaled).
__global__ __launch_bounds__(256) void k_agg1c(const int* __restrict__ rowstart,
                                               const int* __restrict__ rowend,
                                               const int* __restrict__ csr_src,
                                               const f16x8* __restrict__ hw1v,
                                               const float* __restrict__ W2,
                                               const float* __restrict__ b1,
                                               __half* __restrict__ hw2h, int N) {
    __shared__ float sW[128], sb[16];
    int t = threadIdx.x;
    if (t < 128) sW[t] = W2[t];
    if (t < 16)  sb[t] = b1[t];
    __syncthreads();
    int q = t >> 2, j = t & 3;
    int i = blockIdx.x * 64 + q;
    if (i >= N) return;
    int beg = rowstart[i], end = rowend[i];
    int deg = end - beg;
    float di = rsqrtf((float)(deg + 1));
    float a[16];
#pragma unroll
    for (int d = 0; d < 16; ++d) a[d] = 0.f;
    int nfull = deg >> 4;
    int base0 = beg + 4 * j;
    int s4[4];
    if (nfull > 0) {
#pragma unroll
        for (int m = 0; m < 4; ++m) s4[m] = csr_src[base0 + m];
    }
    for (int ch = 0; ch < nfull; ++ch) {
        f16x8 lo[4], hi[4];
#pragma unroll
        for (int m = 0; m < 4; ++m) {
            lo[m] = hw1v[2 * (size_t)s4[m]];
            hi[m] = hw1v[2 * (size_t)s4[m] + 1];
        }
        int sn[4];
        if (ch + 1 < nfull) {      // prefetch next chunk's indices under gathers
#pragma unroll
            for (int m = 0; m < 4; ++m) sn[m] = csr_src[base0 + (ch + 1) * 16 + m];
        }
#pragma unroll
        for (int m = 0; m < 4; ++m) {
#pragma unroll
            for (int d = 0; d < 8; ++d) {
                a[d]     += (float)lo[m][d];
                a[8 + d] += (float)hi[m][d];
            }
        }
        if (ch + 1 < nfull) {
#pragma unroll
            for (int m = 0; m < 4; ++m) s4[m] = sn[m];
        }
    }
    if (deg & 15) {                // masked full-width final chunk
        int cb = beg + nfull * 16 + 4 * j;
        int   sr[4];
        float wr[4];
#pragma unroll
        for (int m = 0; m < 4; ++m) {
            int c = cb + m;
            bool ok = c < end;
            sr[m] = ok ? csr_src[c] : i;   // dummy = self row (hot line), weight 0
            wr[m] = ok ? 1.f : 0.f;
        }
        f16x8 lo[4], hi[4];
#pragma unroll
        for (int m = 0; m < 4; ++m) {
            lo[m] = hw1v[2 * (size_t)sr[m]];
            hi[m] = hw1v[2 * (size_t)sr[m] + 1];
        }
#pragma unroll
        for (int m = 0; m < 4; ++m) {
#pragma unroll
            for (int d = 0; d < 8; ++d) {
                a[d]     += wr[m] * (float)lo[m][d];
                a[8 + d] += wr[m] * (float)hi[m][d];
            }
        }
    }
    if (j == 0) {   // self loop (once per node)
        f16x8 lo = hw1v[2 * (size_t)i];
        f16x8 hi = hw1v[2 * (size_t)i + 1];
#pragma unroll
        for (int d = 0; d < 8; ++d) {
            a[d]     += (float)lo[d];
            a[8 + d] += (float)hi[d];
        }
    }
    // butterfly merge across the quad
#pragma unroll
    for (int d = 0; d < 16; ++d) a[d] += __shfl_xor(a[d], 1, 4);
#pragma unroll
    for (int d = 0; d < 16; ++d) a[d] += __shfl_xor(a[d], 2, 4);
    // fused GEMM2: lane j computes output dims 2j, 2j+1
    float o0 = 0.f, o1 = 0.f;
#pragma unroll
    for (int k = 0; k < 16; ++k) {
        float hv = di * a[k] + sb[k];
        o0 += hv * sW[k * 8 + 2 * j];
        o1 += hv * sW[k * 8 + 2 * j + 1];
    }
    f16x2 ho = {(_Float16)(di * o0), (_Float16)(di * o1)};
    *(f16x2*)&hw2h[(size_t)i * 8 + 2 * j] = ho;   // 4B store, 16B/node across quad
}

// layer-2 (exact R5): 4 lanes/node, 8-dim accumulator, prefetch + masked
// final chunk, butterfly merge, Wl dot + sigmoid.
__global__ __launch_bounds__(256) void k_agg2c(const int* __restrict__ rowstart,
                                               const int* __restrict__ rowend,
                                               const int* __restrict__ csr_src,
                                               const f16x8* __restrict__ hw2v,
                                               const float* __restrict__ Wl,
                                               const float* __restrict__ b2,
                                               const float* __restrict__ bl,
                                               float* __restrict__ z, int N) {
    __shared__ float sW[8], sb[8], sbl;
    int t = threadIdx.x;
    if (t < 8) { sW[t] = Wl[t]; sb[t] = b2[t]; }
    if (t == 0) sbl = bl[0];
    __syncthreads();
    int q = t >> 2, j = t & 3;
    int i = blockIdx.x * 64 + q;
    if (i >= N) return;
    int beg = rowstart[i], end = rowend[i];
    int deg = end - beg;
    float di = rsqrtf((float)(deg + 1));
    float a[8];
#pragma unroll
    for (int d = 0; d < 8; ++d) a[d] = 0.f;
    int nfull = deg >> 4;
    int base0 = beg + 4 * j;
    int s4[4];
    if (nfull > 0) {
#pragma unroll
        for (int m = 0; m < 4; ++m) s4[m] = csr_src[base0 + m];
    }
    for (int ch = 0; ch < nfull; ++ch) {
        f16x8 gv[4];
#pragma unroll
        for (int m = 0; m < 4; ++m) gv[m] = hw2v[(size_t)s4[m]];
        int sn[4];
        if (ch + 1 < nfull) {
#pragma unroll
            for (int m = 0; m < 4; ++m) sn[m] = csr_src[base0 + (ch + 1) * 16 + m];
        }
#pragma unroll
        for (int m = 0; m < 4; ++m)
#pragma unroll
            for (int d = 0; d < 8; ++d) a[d] += (float)gv[m][d];
        if (ch + 1 < nfull) {
#pragma unroll
            for (int m = 0; m < 4; ++m) s4[m] = sn[m];
        }
    }
    if (deg & 15) {
        int cb = beg + nfull * 16 + 4 * j;
        int   sr[4];
        float wr[4];
#pragma unroll
        for (int m = 0; m < 4; ++m) {
            int c = cb + m;
            bool ok = c < end;
            sr[m] = ok ? csr_src[c] : i;
            wr[m] = ok ? 1.f : 0.f;
        }
        f16x8 gv[4];
#pragma unroll
        for (int m = 0; m < 4; ++m) gv[m] = hw2v[(size_t)sr[m]];
#pragma unroll
        for (int m = 0; m < 4; ++m)
#pragma unroll
            for (int d = 0; d < 8; ++d) a[d] += wr[m] * (float)gv[m][d];
    }
    if (j == 0) {
        f16x8 self = hw2v[(size_t)i];
#pragma unroll
        for (int d = 0; d < 8; ++d) a[d] += (float)self[d];
    }
#pragma unroll
    for (int d = 0; d < 8; ++d) a[d] += __shfl_xor(a[d], 1, 4);
#pragma unroll
    for (int d = 0; d < 8; ++d) a[d] += __shfl_xor(a[d], 2, 4);
    if (j == 0) {
        float v = 0.f;
#pragma unroll
        for (int d = 0; d < 8; ++d) {
            float h = di * a[d] + sb[d];
            v += h * sW[d];
        }
        z[i] = 1.f / (1.f + __expf(-(v + sbl)));
    }
}

__global__ __launch_bounds__(256) void k_pred(const int2* __restrict__ pe2,
                                              const float* __restrict__ z,
                                              float* __restrict__ out, int P) {
    int p = blockIdx.x * 256 + threadIdx.x;
    if (p < P) {
        int2 e = pe2[p];
        out[p] = z[e.x] * z[e.y];
    }
}

// ---------------- launch ----------------

extern "C" void kernel_launch(void* const* d_in, const int* in_sizes, int n_in,
                              void* d_out, int out_size, void* d_ws, size_t ws_size,
                              hipStream_t stream) {
    const float* x  = (const float*)d_in[0];
    const int*   ei = (const int*)d_in[1];
    const int*   pe = (const int*)d_in[2];
    const float* W1 = (const float*)d_in[3];
    const float* b1 = (const float*)d_in[4];
    const float* W2 = (const float*)d_in[5];
    const float* b2 = (const float*)d_in[6];
    const float* Wl = (const float*)d_in[7];
    const float* bl = (const float*)d_in[8];
    float* out = (float*)d_out;

    const int N = in_sizes[0] / 128;
    const int E = in_sizes[1] / 2;
    const int P = in_sizes[2] / 2;
    const int NBUK = (N + BUCK - 1) >> BSHIFT;   // 391 for N=100000

    const int* src = ei;
    const int* dst = ei + E;

    // workspace (4B words), ~45 MB:
    float*  ws   = (float*)d_ws;
    float*  dinv = ws;                               // N
    __half* hw1h = (__half*)(ws + (size_t)N);        // 16N halves = 8N words (16B-aligned)
    __half* hw2h = (__half*)(ws + (size_t)9 * N);    // 8N halves = 4N words
    float*  z    = ws + (size_t)13 * N;              // N
    int* rowstart = (int*)(ws + (size_t)14 * N);     // N
    int* rowend   = rowstart + N;                    // N
    int* bcursor  = rowend + N;                      // NBUK
    int* binned   = bcursor + 512;                   // NBUK*CAP (sparse)
    int* csr_src  = binned + (size_t)NBUK * CAP;     // NBUK*CAP (sparse)

    const int B = 256;

    k_curinit<<<(NBUK + B - 1) / B, B, 0, stream>>>(bcursor, NBUK);
    k_binscatter<<<(E + TILE - 1) / TILE, 1024, 0, stream>>>(src, dst, bcursor, binned, E, NBUK);
    k_sortbucket<<<NBUK, 1024, 0, stream>>>(bcursor, binned, csr_src, rowstart, rowend, dinv, N);
    k_gemm1<<<(N + 63) / 64, B, 0, stream>>>(x, W1, dinv, hw1h, N);
    k_agg1c<<<(N + 63) / 64, B, 0, stream>>>(rowstart, rowend, csr_src,
                                             (const f16x8*)hw1h, W2, b1, hw2h, N);
    k_agg2c<<<(N + 63) / 64, B, 0, stream>>>(rowstart, rowend, csr_src,
                                             (const f16x8*)hw2h, Wl, b2, bl, z, N);
    k_pred<<<(P + B - 1) / B, B, 0, stream>>>((const int2*)pe, z, out, P);
}